// Round 5
// baseline (297.787 us; speedup 1.0000x reference)
//
#include <hip/hip_runtime.h>

// QuantileLoss: scalar = ( sum_rows[ (p0-t0)^2+(p1-t1)^2+(p2-t2)^2 + 2*lower ] ) / (5N)
// lower = p3>p2 ? 1000 : (p3 > 0.95*t2 ? 0 : (p3-0.95*t2)^2)
//
// R1 normal/row loads:            kernel 101 us, effective read ~2.65 TB/s
// R2 normal/coalesced+LDS:        105 us, same            -> coalescing not the limiter
// R3 NT/register, 160B/thread:    150 us, pins 2.68 TB/s + 1.46x over-fetch
// R4 NT/coalesced+LDS+pipeline:   ~88 us, ~3.1 TB/s       -> caching mode not the limiter
// Invariant across R1-R4: reads return through the VGPR load-return path, all cap ~3 TB/s.
// Harness 0xAA fill proves 6.9 TB/s one-direction is achievable (store path).
// R5: bypass the VGPR return path entirely: global_load_lds width=16 (L2->LDS direct),
// cached policy (L3 hits help), wave-uniform-base + lane*16 layout (required form),
// single 32KB buffer -> 4 blocks/CU, block TLP hides latency, __syncthreads = vmcnt(0) drain.

#define NROWS 8388608                      // 2^23
#define ROWS_PER_CHUNK 1024
#define NCHUNKS (NROWS / ROWS_PER_CHUNK)   // 8192
#define PCHUNK (ROWS_PER_CHUNK * 5)        // 5120 floats = 20 KB
#define TCHUNK (ROWS_PER_CHUNK * 3)        // 3072 floats = 12 KB
#define GRID 2048
#define CHUNKS_PER_BLOCK (NCHUNKS / GRID)  // 4

typedef float v4f __attribute__((ext_vector_type(4)));

__device__ __forceinline__ void async_copy16(const v4f* g, v4f* l)
{
    __builtin_amdgcn_global_load_lds(
        (const __attribute__((address_space(1))) void*)g,
        (__attribute__((address_space(3))) void*)l,
        16, 0, 0);
}

__global__ void __launch_bounds__(256) qloss_partial(
    const float* __restrict__ preds,
    const float* __restrict__ target,
    double* __restrict__ ws)
{
    __shared__ float sp[PCHUNK];
    __shared__ float st[TCHUNK];

    const int t = threadIdx.x;
    double acc = 0.0;

    for (int i = 0; i < CHUNKS_PER_BLOCK; ++i) {
        const int c = blockIdx.x + i * GRID;
        const v4f* gp = (const v4f*)(preds + (size_t)c * PCHUNK);
        const v4f* gt = (const v4f*)(target + (size_t)c * TCHUNK);

        // Async global->LDS, 16B per lane. LDS dest = wave-uniform base + lane*16:
        // index t + k*256 = (wave*64 + k*256) + lane  -> satisfied.
        #pragma unroll
        for (int k = 0; k < 5; ++k)
            async_copy16(gp + t + k * 256, (v4f*)sp + t + k * 256);
        #pragma unroll
        for (int k = 0; k < 3; ++k)
            async_copy16(gt + t + k * 256, (v4f*)st + t + k * 256);

        __syncthreads();   // compiler emits s_waitcnt vmcnt(0) before s_barrier

        // Compute 4 rows/thread out of LDS (stride 5/3: 2-way bank alias, free).
        float sum = 0.0f;
        #pragma unroll
        for (int rr = 0; rr < 4; ++rr) {
            const int r = t + rr * 256;
            const float p0 = sp[5*r + 0];
            const float p1 = sp[5*r + 1];
            const float p2 = sp[5*r + 2];
            const float p3 = sp[5*r + 3];
            const float t0 = st[3*r + 0];
            const float t1 = st[3*r + 1];
            const float t2 = st[3*r + 2];

            const float a0 = p0 - t0;
            const float a1 = p1 - t1;
            const float a2 = p2 - t2;
            const float m  = a0*a0 + a1*a1 + a2*a2;

            const float q = t2 * 0.95f;
            const float d = p3 - q;
            const float lower = (p3 > p2) ? 1000.0f : ((p3 > q) ? 0.0f : d * d);

            sum += m + 2.0f * lower;
        }
        acc += (double)sum;

        __syncthreads();   // LDS safe to overwrite next iteration
    }

    // wave64 shuffle reduce
    #pragma unroll
    for (int off = 32; off > 0; off >>= 1)
        acc += __shfl_down(acc, off, 64);

    __shared__ double red[4];
    const int lane = t & 63;
    const int wave = t >> 6;
    if (lane == 0) red[wave] = acc;
    __syncthreads();

    if (t == 0)
        atomicAdd(ws, red[0] + red[1] + red[2] + red[3]);   // 2048 atomics total
}

__global__ void qloss_final(const double* __restrict__ ws, float* __restrict__ out)
{
    *out = (float)(*ws / (5.0 * (double)NROWS));
}

extern "C" void kernel_launch(void* const* d_in, const int* in_sizes, int n_in,
                              void* d_out, int out_size, void* d_ws, size_t ws_size,
                              hipStream_t stream)
{
    const float* preds  = (const float*)d_in[0];
    const float* target = (const float*)d_in[1];
    float* out  = (float*)d_out;
    double* ws  = (double*)d_ws;

    // d_ws is re-poisoned to 0xAA before every timed launch — zero the accumulator.
    hipMemsetAsync(ws, 0, sizeof(double), stream);

    qloss_partial<<<GRID, 256, 0, stream>>>(preds, target, ws);
    qloss_final<<<1, 1, 0, stream>>>(ws, out);
}